// Round 10
// baseline (98.887 us; speedup 1.0000x reference)
//
#include <hip/hip_runtime.h>
#include <stdint.h>

#define B_ 2
#define N_ 16384
#define P_ 1024
#define C_ 256
#define S_ 64
#define CH_ (C_ + 3)   // 259 output channels
#define CAP_ 512       // key-buffer capacity for selection

#define INF_BITS 0x7F800000u
#define SMEM_BYTES (64 * 65 * 4)   // 16640 B dynamic LDS (max of both paths)

typedef unsigned long long u64;

struct QS {
    u64 keys[CAP_];         // 4 KB
    uint32_t hist[4][256];  // 4 KB (per-wave split histograms)
    u64 red[4];
    uint32_t wsum[4];
    int vflag[128];         // validity of n in [0,128) (for the fill step)
    int s_idx[S_];
    int cnt;
    int sel;
    uint32_t k;
};
static_assert(sizeof(QS) <= SMEM_BYTES, "QS too big");

__device__ __forceinline__ u64 umin64(u64 a, u64 b) { return a < b ? a : b; }

// bf16 round-to-nearest-even (values are finite normals here)
__device__ __forceinline__ uint32_t f2bf(float f) {
    uint32_t x = __float_as_uint(f);
    return (x + 0x7fffu + ((x >> 16) & 1u)) >> 16;
}
__device__ __forceinline__ float bf2f(uint32_t u) { return __uint_as_float(u << 16); }

// Block-wide (256 threads) min of u64 keys. Contains barriers; call uniformly.
__device__ u64 block_min_u64(u64 v, u64* s_red) {
    int tid = threadIdx.x;
#pragma unroll
    for (int o = 32; o > 0; o >>= 1)
        v = umin64(v, (u64)__shfl_xor(v, o, 64));
    __syncthreads();
    if ((tid & 63) == 0) s_red[tid >> 6] = v;
    __syncthreads();
    u64 r = s_red[0];
#pragma unroll
    for (int w = 1; w < 4; ++w) r = umin64(r, s_red[w]);
    return r;
}

// Exact score (bit-identical to reference order; no FMA contraction).
__device__ __forceinline__ uint32_t eval_sb(float px, float py, float pz,
                                            float cx, float cy, float cz,
                                            float r0, float r1, float r2,
                                            float r3, float r4, float r5,
                                            float r6, float r7, float r8) {
    float dx = px - cx, dy = py - cy, dz = pz - cz;
    float xr = __fadd_rn(__fadd_rn(__fmul_rn(dx, r0), __fmul_rn(dy, r1)), __fmul_rn(dz, r2));
    float yr = __fadd_rn(__fadd_rn(__fmul_rn(dx, r3), __fmul_rn(dy, r4)), __fmul_rn(dz, r5));
    float zr = __fadd_rn(__fadd_rn(__fmul_rn(dx, r6), __fmul_rn(dy, r7)), __fmul_rn(dz, r8));
    float rad2 = __fadd_rn(__fmul_rn(yr, yr), __fmul_rn(zr, zr));
    float radial = __fsqrt_rn(fmaxf(rad2, 0.0f));
    bool valid = (radial <= 0.05f) && (xr >= -0.02f) && (xr <= 0.04f);
    float score = __fadd_rn(radial, __fmul_rn(1e-3f, fabsf(xr)));
    return valid ? __float_as_uint(score) : INF_BITS;
}

__device__ __forceinline__ uint32_t score_bits(const float* __restrict__ xb, int n,
                                               float cx, float cy, float cz,
                                               float r0, float r1, float r2,
                                               float r3, float r4, float r5,
                                               float r6, float r7, float r8) {
    return eval_sb(xb[n * 3 + 0], xb[n * 3 + 1], xb[n * 3 + 2],
                   cx, cy, cz, r0, r1, r2, r3, r4, r5, r6, r7, r8);
}

// ---------------- transpose path: one 64x64 tile of (B,C,N) -> (B,N,C) bf16 ----------------
__device__ __noinline__ void do_transpose(char* smem, const float* __restrict__ feat,
                                          ushort* __restrict__ featT, int t) {
    float(*tile)[65] = (float(*)[65])smem;
    const int tid = threadIdx.x;
    int b = t >> 10;
    int rem = t & 1023;
    int cblk = rem >> 8;   // 0..3
    int nblk = rem & 255;  // 0..255
    for (int i = tid; i < 64 * 64; i += 256) {
        int cy = i >> 6, nx = i & 63;
        tile[cy][nx] = feat[((size_t)(b * C_ + cblk * 64 + cy)) * N_ + nblk * 64 + nx];
    }
    __syncthreads();
    for (int i = tid; i < 64 * 32; i += 256) {
        int ny = i >> 5, cp = i & 31;
        uint32_t u0 = f2bf(tile[2 * cp + 0][ny]);
        uint32_t u1 = f2bf(tile[2 * cp + 1][ny]);
        *(uint32_t*)&featT[((size_t)(b * N_ + nblk * 64 + ny)) * C_ + cblk * 64 + 2 * cp] =
            u0 | (u1 << 16);
    }
}

// ---------------- query path: one bp; writes idx + 3 xyz channels ----------------
__device__ __noinline__ void do_query(char* smem, const float* __restrict__ xyz,
                                      const float* __restrict__ new_xyz,
                                      const float* __restrict__ rot,
                                      int* __restrict__ idx_out,
                                      float* __restrict__ out, int bp) {
    QS& qs = *(QS*)smem;
    const int tid = threadIdx.x;
    const int lane = tid & 63;
    const int wid = tid >> 6;
    const int b = bp >> 10;
    const int p = bp & 1023;

    if (tid == 0) qs.cnt = 0;

    const float cx = new_xyz[bp * 3 + 0];
    const float cy = new_xyz[bp * 3 + 1];
    const float cz = new_xyz[bp * 3 + 2];
    const float* R = rot + (size_t)bp * 9;
    const float r0 = R[0], r1 = R[1], r2 = R[2];
    const float r3 = R[3], r4 = R[4], r5 = R[5];
    const float r6 = R[6], r7 = R[7], r8 = R[8];

    __syncthreads();  // cnt initialized

    const float* xb = xyz + (size_t)b * N_ * 3;
    const float4* xb4 = (const float4*)xb;

    // main pass: 4 points/thread/iter via 3x dwordx4; wave-aggregated compaction
    for (int it = 0; it < N_ / 1024; ++it) {
        int t4 = it * 256 + tid;
        float4 A = xb4[t4 * 3 + 0];
        float4 Bv = xb4[t4 * 3 + 1];
        float4 Cv = xb4[t4 * 3 + 2];
        int n0 = t4 * 4;

        uint32_t s0 = eval_sb(A.x, A.y, A.z, cx, cy, cz, r0, r1, r2, r3, r4, r5, r6, r7, r8);
        uint32_t s1 = eval_sb(A.w, Bv.x, Bv.y, cx, cy, cz, r0, r1, r2, r3, r4, r5, r6, r7, r8);
        uint32_t s2 = eval_sb(Bv.z, Bv.w, Cv.x, cx, cy, cz, r0, r1, r2, r3, r4, r5, r6, r7, r8);
        uint32_t s3 = eval_sb(Cv.y, Cv.z, Cv.w, cx, cy, cz, r0, r1, r2, r3, r4, r5, r6, r7, r8);

        if (it == 0 && tid < 32) {
            qs.vflag[n0 + 0] = (s0 != INF_BITS) ? 1 : 0;
            qs.vflag[n0 + 1] = (s1 != INF_BITS) ? 1 : 0;
            qs.vflag[n0 + 2] = (s2 != INF_BITS) ? 1 : 0;
            qs.vflag[n0 + 3] = (s3 != INF_BITS) ? 1 : 0;
        }
        uint32_t mn = min(min(s0, s1), min(s2, s3));
        if (__any(mn != INF_BITS)) {
            uint32_t sb[4] = {s0, s1, s2, s3};
#pragma unroll
            for (int j = 0; j < 4; ++j) {
                u64 m = __ballot(sb[j] != INF_BITS);
                if (m) {  // wave-uniform
                    int leader = __builtin_ctzll(m);
                    int cnt = __popcll(m);
                    int base = 0;
                    if (lane == leader) base = atomicAdd(&qs.cnt, cnt);
                    base = __shfl(base, leader, 64);
                    if (sb[j] != INF_BITS) {
                        int pos = base + __popcll(m & ((1ull << lane) - 1ull));
                        if (pos < CAP_) qs.keys[pos] = ((u64)sb[j] << 32) | (unsigned)(n0 + j);
                    }
                }
            }
        }
    }
    __syncthreads();
    const int v = qs.cnt;
    int* s_out = qs.s_idx;

    if (v == 0) {
        // rare: no point in cylinder -> every slot = argmin d2 (first occurrence)
        u64 fb = ~0ull;
        for (int n = tid; n < N_; n += 256) {
            float px = xb[n * 3 + 0], py = xb[n * 3 + 1], pz = xb[n * 3 + 2];
            float dx = px - cx, dy = py - cy, dz = pz - cz;
            float d2 = __fadd_rn(__fadd_rn(__fmul_rn(dx, dx), __fmul_rn(dy, dy)),
                                 __fmul_rn(dz, dz));
            fb = umin64(fb, ((u64)__float_as_uint(d2) << 32) | (unsigned)n);
        }
        u64 m = block_min_u64(fb, qs.red);
        if (tid < S_) s_out[tid] = (int)(unsigned)(m & 0xFFFFFFFFu);
    } else if (v <= 64) {
        // pad to 64 with unique huge keys (real idx < 0x4000, pads >= 0x10000)
        if (tid >= v && tid < 64)
            qs.keys[tid] = 0xFFFFFFFF00000000ull | (unsigned)(0x10000 + tid);
        __syncthreads();
        u64 key = 0;
        int rank = 0;
        if (tid < 64) {
            key = qs.keys[tid];
            for (int o = 0; o < 64; ++o) rank += (qs.keys[o] < key) ? 1 : 0;
        }
        __syncthreads();
        if (tid < 64) qs.keys[rank] = key;
        __syncthreads();
        // fill remaining slots with smallest-index invalid points (ascending).
        // v <= 63 when needed>0, so n in [0,128) holds >= 65 invalid points.
        const int needed = 64 - v;
        if (tid < 64 && needed > 0) {
            bool inv0 = (qs.vflag[tid] == 0);
            u64 m0 = __ballot(inv0);
            int before0 = __popcll(m0 & ((1ull << tid) - 1ull));
            if (inv0 && before0 < needed) qs.keys[v + before0] = (unsigned)tid;
            int c0 = __popcll(m0);
            if (c0 < needed) {
                bool inv1 = (qs.vflag[64 + tid] == 0);
                u64 m1 = __ballot(inv1);
                int b1 = c0 + __popcll(m1 & ((1ull << tid) - 1ull));
                if (inv1 && b1 < needed) qs.keys[v + b1] = (unsigned)(64 + tid);
            }
        }
        __syncthreads();
        if (tid < S_) s_out[tid] = (int)(unsigned)(qs.keys[tid] & 0xFFFFFFFFu);
    } else if (v <= CAP_) {
        // all valid keys already compacted; rank-sort, emit ranks < 64
        for (int i = tid; i < v; i += 256) {
            u64 key = qs.keys[i];
            int rank = 0;
            for (int j = 0; j < v; ++j) rank += (qs.keys[j] < key) ? 1 : 0;
            if (rank < 64) s_out[rank] = (int)(unsigned)(key & 0xFFFFFFFFu);
        }
    } else {
        // rare: v > CAP_. 4-pass radix select of 64th-smallest score (recompute).
        uint32_t prefix = 0, mask = 0, kk = 64;
        for (int pass = 0; pass < 4; ++pass) {
            const int shift = 24 - 8 * pass;
            __syncthreads();
            qs.hist[0][tid] = 0;
            qs.hist[1][tid] = 0;
            qs.hist[2][tid] = 0;
            qs.hist[3][tid] = 0;
            __syncthreads();
            for (int n = tid; n < N_; n += 256) {
                uint32_t sb = score_bits(xb, n, cx, cy, cz, r0, r1, r2, r3, r4, r5, r6, r7, r8);
                if (sb != INF_BITS && (sb & mask) == prefix)
                    atomicAdd(&qs.hist[wid][(sb >> shift) & 255u], 1u);
            }
            __syncthreads();
            uint32_t cnt = qs.hist[0][tid] + qs.hist[1][tid] + qs.hist[2][tid] + qs.hist[3][tid];
            uint32_t x = cnt;
#pragma unroll
            for (int o = 1; o < 64; o <<= 1) {
                uint32_t y = __shfl_up(x, o, 64);
                if ((tid & 63) >= o) x += y;
            }
            if ((tid & 63) == 63) qs.wsum[wid] = x;
            __syncthreads();
            uint32_t woff = 0;
            for (int w = 0; w < wid; ++w) woff += qs.wsum[w];
            uint32_t incl = x + woff;
            uint32_t excl = incl - cnt;
            if (kk > excl && kk <= incl) {  // exactly one thread
                qs.sel = tid;
                qs.k = kk - excl;
            }
            __syncthreads();
            prefix |= ((uint32_t)qs.sel) << shift;
            mask |= 255u << shift;
            kk = qs.k;
        }
        const uint32_t T = prefix;  // exact 64th-smallest score bits

        __syncthreads();
        if (tid == 0) qs.cnt = 0;
        __syncthreads();
        for (int n = tid; n < N_; n += 256) {
            uint32_t sb = score_bits(xb, n, cx, cy, cz, r0, r1, r2, r3, r4, r5, r6, r7, r8);
            if (sb != INF_BITS && sb <= T) {
                int pos = atomicAdd(&qs.cnt, 1);
                if (pos < CAP_) qs.keys[pos] = ((u64)sb << 32) | (unsigned)n;
            }
        }
        __syncthreads();
        int c = qs.cnt;
        if (c > CAP_) c = CAP_;  // unreachable without >448 exact float ties
        for (int i = tid; i < c; i += 256) {
            u64 key = qs.keys[i];
            int rank = 0;
            for (int j = 0; j < c; ++j) rank += (qs.keys[j] < key) ? 1 : 0;
            if (rank < 64) s_out[rank] = (int)(unsigned)(key & 0xFFFFFFFFu);
        }
    }
    __syncthreads();  // s_idx visible to all

    // idx out + 3 xyz output channels
    if (tid < S_) {
        int n = s_out[tid];
        idx_out[(size_t)bp * S_ + tid] = n;
        const float* pt = xyz + ((size_t)b * N_ + n) * 3;
        float dx = pt[0] - cx;
        float dy = pt[1] - cy;
        float dz = pt[2] - cz;
        // g_e = ((dx*R[0,e] + dy*R[1,e]) + dz*R[2,e]), no FMA
        float g0 = __fadd_rn(__fadd_rn(__fmul_rn(dx, r0), __fmul_rn(dy, r3)), __fmul_rn(dz, r6));
        float g1 = __fadd_rn(__fadd_rn(__fmul_rn(dx, r1), __fmul_rn(dy, r4)), __fmul_rn(dz, r7));
        float g2 = __fadd_rn(__fadd_rn(__fmul_rn(dx, r2), __fmul_rn(dy, r5)), __fmul_rn(dz, r8));
        out[(((size_t)b * CH_ + 0) * P_ + p) * S_ + tid] = g0;
        out[(((size_t)b * CH_ + 1) * P_ + p) * S_ + tid] = g1;
        out[(((size_t)b * CH_ + 2) * P_ + p) * S_ + tid] = g2;
    }
}

// ---------------- kernel 1: parity-specialized query (even) / transpose (odd) ----------------
__global__ __launch_bounds__(256) void tq_kernel(const float* __restrict__ feat,
                                                 ushort* __restrict__ featT,
                                                 const float* __restrict__ xyz,
                                                 const float* __restrict__ new_xyz,
                                                 const float* __restrict__ rot,
                                                 int* __restrict__ idx_out,
                                                 float* __restrict__ out, int useT) {
    extern __shared__ char smem[];
    const int id = blockIdx.x >> 1;
    if (blockIdx.x & 1) {
        if (useT) do_transpose(smem, feat, featT, id);
    } else {
        do_query(smem, xyz, new_xyz, rot, idx_out, out, id);
    }
}

// ---------------- kernel 2: feature gather + store (round-7 tile scheme) ----------------
__global__ __launch_bounds__(256) void group_kernel(const ushort* __restrict__ featT,
                                                    const float* __restrict__ features,
                                                    const int* __restrict__ idx,
                                                    float* __restrict__ out, int useT) {
    __shared__ uint32_t tileu[32][130];  // 16.6 KB; [sample][channel-pair]
    __shared__ int s_idx[S_];
    const int tid = threadIdx.x;
    const int bp = blockIdx.x;
    const int b = bp >> 10;
    const int p = bp & 1023;

    if (tid < S_) s_idx[tid] = idx[(size_t)bp * S_ + tid];
    __syncthreads();

    for (int h = 0; h < 2; ++h) {
        if (h) __syncthreads();  // protect tile reuse
        if (useT) {
            // uint2 per lane (4 channel-pairs); 512B per gathered row; b64 LDS writes
            for (int i = tid; i < 32 * 64; i += 256) {
                int sl = i >> 6, cd = i & 63;
                int n = s_idx[h * 32 + sl];
                uint2 v = *(const uint2*)&featT[((size_t)b * N_ + n) * C_ + cd * 4];
                *(uint2*)&tileu[sl][cd * 2] = v;
            }
        } else {
            // fallback (no workspace): scalar gathers from (C,N), pack to bf16
            for (int i = tid; i < 32 * 128; i += 256) {
                int sl = i >> 7, cp = i & 127;
                int n = s_idx[h * 32 + sl];
                uint32_t u0 = f2bf(features[((size_t)b * C_ + 2 * cp + 0) * N_ + n]);
                uint32_t u1 = f2bf(features[((size_t)b * C_ + 2 * cp + 1) * N_ + n]);
                tileu[sl][cp] = u0 | (u1 << 16);
            }
        }
        __syncthreads();
        // each thread reads 4 uints (2-way LDS, free) -> two float4 stores
        for (int i = tid; i < (C_ / 2) * 8; i += 256) {
            int cp = i >> 3, q = i & 7;
            uint32_t u0 = tileu[4 * q + 0][cp];
            uint32_t u1 = tileu[4 * q + 1][cp];
            uint32_t u2 = tileu[4 * q + 2][cp];
            uint32_t u3 = tileu[4 * q + 3][cp];
            float4 lo, hi;
            lo.x = bf2f(u0 & 0xffffu); lo.y = bf2f(u1 & 0xffffu);
            lo.z = bf2f(u2 & 0xffffu); lo.w = bf2f(u3 & 0xffffu);
            hi.x = bf2f(u0 >> 16); hi.y = bf2f(u1 >> 16);
            hi.z = bf2f(u2 >> 16); hi.w = bf2f(u3 >> 16);
            size_t base0 = (((size_t)b * CH_ + 3 + 2 * cp) * P_ + p) * S_ + h * 32 + 4 * q;
            *(float4*)&out[base0] = lo;
            *(float4*)&out[base0 + (size_t)P_ * S_] = hi;
        }
    }
}

extern "C" void kernel_launch(void* const* d_in, const int* in_sizes, int n_in,
                              void* d_out, int out_size, void* d_ws, size_t ws_size,
                              hipStream_t stream) {
    const float* xyz = (const float*)d_in[0];       // (B,N,3)
    const float* new_xyz = (const float*)d_in[1];   // (B,P,3)
    const float* rot = (const float*)d_in[2];       // (B,P,3,3)
    const float* features = (const float*)d_in[3];  // (B,C,N)
    float* out = (float*)d_out;

    const size_t featT_bytes = (size_t)B_ * N_ * C_ * sizeof(ushort);  // 16.8 MB
    const size_t idx_bytes = (size_t)B_ * P_ * S_ * sizeof(int);       // 512 KB
    const int useT = (ws_size >= featT_bytes + idx_bytes) ? 1 : 0;

    ushort* featT = (ushort*)d_ws;
    int* idx = useT ? (int*)((char*)d_ws + featT_bytes) : (int*)d_ws;

    tq_kernel<<<2 * B_ * P_, 256, SMEM_BYTES, stream>>>(features, featT, xyz, new_xyz, rot,
                                                        idx, out, useT);
    group_kernel<<<B_ * P_, 256, 0, stream>>>(featT, features, idx, out, useT);
}

// Round 11
// 64.129 us; speedup vs baseline: 1.5420x; 1.5420x over previous
//
#include <hip/hip_runtime.h>
#include <stdint.h>

#define B_ 2
#define N_ 16384
#define P_ 1024
#define C_ 256
#define S_ 64
#define CH_ (C_ + 3)   // 259 output channels
#define CAP_ 512       // key-buffer capacity for selection

#define INF_BITS 0x7F800000u

typedef unsigned long long u64;

struct QS {
    u64 keys[CAP_];         // 4 KB
    uint32_t hist[4][256];  // 4 KB (per-wave split histograms)
    u64 red[4];
    uint32_t wsum[4];
    int vflag[128];         // validity of n in [0,128) (for the fill step)
    int cnt;
    int sel;
    uint32_t k;
};

struct GT {
    uint32_t tileu[32][130];  // 16.6 KB; [sample][channel-pair], bf16x2 packed
};

union USmem {
    QS qs;
    GT g;
};

__device__ __forceinline__ u64 umin64(u64 a, u64 b) { return a < b ? a : b; }

// bf16 round-to-nearest-even (values are finite normals here)
__device__ __forceinline__ uint32_t f2bf(float f) {
    uint32_t x = __float_as_uint(f);
    return (x + 0x7fffu + ((x >> 16) & 1u)) >> 16;
}
__device__ __forceinline__ float bf2f(uint32_t u) { return __uint_as_float(u << 16); }

// Block-wide (256 threads) min of u64 keys. Contains barriers; call uniformly.
__device__ u64 block_min_u64(u64 v, u64* s_red) {
    int tid = threadIdx.x;
#pragma unroll
    for (int o = 32; o > 0; o >>= 1)
        v = umin64(v, (u64)__shfl_xor(v, o, 64));
    __syncthreads();
    if ((tid & 63) == 0) s_red[tid >> 6] = v;
    __syncthreads();
    u64 r = s_red[0];
#pragma unroll
    for (int w = 1; w < 4; ++w) r = umin64(r, s_red[w]);
    return r;
}

// Exact score (bit-identical to reference order; no FMA contraction).
__device__ __forceinline__ uint32_t eval_sb(float px, float py, float pz,
                                            float cx, float cy, float cz,
                                            float r0, float r1, float r2,
                                            float r3, float r4, float r5,
                                            float r6, float r7, float r8) {
    float dx = px - cx, dy = py - cy, dz = pz - cz;
    float xr = __fadd_rn(__fadd_rn(__fmul_rn(dx, r0), __fmul_rn(dy, r1)), __fmul_rn(dz, r2));
    float yr = __fadd_rn(__fadd_rn(__fmul_rn(dx, r3), __fmul_rn(dy, r4)), __fmul_rn(dz, r5));
    float zr = __fadd_rn(__fadd_rn(__fmul_rn(dx, r6), __fmul_rn(dy, r7)), __fmul_rn(dz, r8));
    float rad2 = __fadd_rn(__fmul_rn(yr, yr), __fmul_rn(zr, zr));
    float radial = __fsqrt_rn(fmaxf(rad2, 0.0f));
    bool valid = (radial <= 0.05f) && (xr >= -0.02f) && (xr <= 0.04f);
    float score = __fadd_rn(radial, __fmul_rn(1e-3f, fabsf(xr)));
    return valid ? __float_as_uint(score) : INF_BITS;
}

__device__ __forceinline__ uint32_t score_bits(const float* __restrict__ xb, int n,
                                               float cx, float cy, float cz,
                                               float r0, float r1, float r2,
                                               float r3, float r4, float r5,
                                               float r6, float r7, float r8) {
    return eval_sb(xb[n * 3 + 0], xb[n * 3 + 1], xb[n * 3 + 2],
                   cx, cy, cz, r0, r1, r2, r3, r4, r5, r6, r7, r8);
}

// Selection for one query -> writes 64 indices to s_out (LDS).
// Branch choice is block-uniform (v in LDS); barriers OK. No early returns.
__device__ void select_idx(QS& qs, const float* __restrict__ xb,
                           float cx, float cy, float cz,
                           float r0, float r1, float r2, float r3, float r4,
                           float r5, float r6, float r7, float r8,
                           int* s_out) {
    const int tid = threadIdx.x;
    const int wid = tid >> 6;
    const int v = qs.cnt;

    if (v == 0) {
        // rare: no point in cylinder -> every slot = argmin d2 (first occurrence)
        u64 fb = ~0ull;
        for (int n = tid; n < N_; n += 256) {
            float px = xb[n * 3 + 0], py = xb[n * 3 + 1], pz = xb[n * 3 + 2];
            float dx = px - cx, dy = py - cy, dz = pz - cz;
            float d2 = __fadd_rn(__fadd_rn(__fmul_rn(dx, dx), __fmul_rn(dy, dy)),
                                 __fmul_rn(dz, dz));
            fb = umin64(fb, ((u64)__float_as_uint(d2) << 32) | (unsigned)n);
        }
        u64 m = block_min_u64(fb, qs.red);
        if (tid < S_) s_out[tid] = (int)(unsigned)(m & 0xFFFFFFFFu);
    } else if (v <= 64) {
        // pad to 64 with unique huge keys (real idx < 0x4000, pads >= 0x10000)
        if (tid >= v && tid < 64)
            qs.keys[tid] = 0xFFFFFFFF00000000ull | (unsigned)(0x10000 + tid);
        __syncthreads();
        u64 key = 0;
        int rank = 0;
        if (tid < 64) {
            key = qs.keys[tid];
            for (int o = 0; o < 64; ++o) rank += (qs.keys[o] < key) ? 1 : 0;
        }
        __syncthreads();
        if (tid < 64) qs.keys[rank] = key;
        __syncthreads();
        // fill remaining slots with smallest-index invalid points (ascending).
        // v <= 63 when needed>0, so n in [0,128) holds >= 65 invalid points.
        const int needed = 64 - v;
        if (tid < 64 && needed > 0) {
            bool inv0 = (qs.vflag[tid] == 0);
            u64 m0 = __ballot(inv0);
            int before0 = __popcll(m0 & ((1ull << tid) - 1ull));
            if (inv0 && before0 < needed) qs.keys[v + before0] = (unsigned)tid;
            int c0 = __popcll(m0);
            if (c0 < needed) {
                bool inv1 = (qs.vflag[64 + tid] == 0);
                u64 m1 = __ballot(inv1);
                int b1 = c0 + __popcll(m1 & ((1ull << tid) - 1ull));
                if (inv1 && b1 < needed) qs.keys[v + b1] = (unsigned)(64 + tid);
            }
        }
        __syncthreads();
        if (tid < S_) s_out[tid] = (int)(unsigned)(qs.keys[tid] & 0xFFFFFFFFu);
    } else if (v <= CAP_) {
        // all valid keys already compacted; rank-sort, emit ranks < 64
        for (int i = tid; i < v; i += 256) {
            u64 key = qs.keys[i];
            int rank = 0;
            for (int j = 0; j < v; ++j) rank += (qs.keys[j] < key) ? 1 : 0;
            if (rank < 64) s_out[rank] = (int)(unsigned)(key & 0xFFFFFFFFu);
        }
    } else {
        // rare: v > CAP_. 4-pass radix select of 64th-smallest score (recompute).
        uint32_t prefix = 0, mask = 0, kk = 64;
        for (int pass = 0; pass < 4; ++pass) {
            const int shift = 24 - 8 * pass;
            __syncthreads();
            qs.hist[0][tid] = 0;
            qs.hist[1][tid] = 0;
            qs.hist[2][tid] = 0;
            qs.hist[3][tid] = 0;
            __syncthreads();
            for (int n = tid; n < N_; n += 256) {
                uint32_t sb = score_bits(xb, n, cx, cy, cz, r0, r1, r2, r3, r4, r5, r6, r7, r8);
                if (sb != INF_BITS && (sb & mask) == prefix)
                    atomicAdd(&qs.hist[wid][(sb >> shift) & 255u], 1u);
            }
            __syncthreads();
            uint32_t cnt = qs.hist[0][tid] + qs.hist[1][tid] + qs.hist[2][tid] + qs.hist[3][tid];
            uint32_t x = cnt;
#pragma unroll
            for (int o = 1; o < 64; o <<= 1) {
                uint32_t y = __shfl_up(x, o, 64);
                if ((tid & 63) >= o) x += y;
            }
            if ((tid & 63) == 63) qs.wsum[wid] = x;
            __syncthreads();
            uint32_t woff = 0;
            for (int w = 0; w < wid; ++w) woff += qs.wsum[w];
            uint32_t incl = x + woff;
            uint32_t excl = incl - cnt;
            if (kk > excl && kk <= incl) {  // exactly one thread
                qs.sel = tid;
                qs.k = kk - excl;
            }
            __syncthreads();
            prefix |= ((uint32_t)qs.sel) << shift;
            mask |= 255u << shift;
            kk = qs.k;
        }
        const uint32_t T = prefix;  // exact 64th-smallest score bits

        __syncthreads();
        if (tid == 0) qs.cnt = 0;
        __syncthreads();
        for (int n = tid; n < N_; n += 256) {
            uint32_t sb = score_bits(xb, n, cx, cy, cz, r0, r1, r2, r3, r4, r5, r6, r7, r8);
            if (sb != INF_BITS && sb <= T) {
                int pos = atomicAdd(&qs.cnt, 1);
                if (pos < CAP_) qs.keys[pos] = ((u64)sb << 32) | (unsigned)n;
            }
        }
        __syncthreads();
        int c = qs.cnt;
        if (c > CAP_) c = CAP_;  // unreachable without >448 exact float ties
        for (int i = tid; i < c; i += 256) {
            u64 key = qs.keys[i];
            int rank = 0;
            for (int j = 0; j < c; ++j) rank += (qs.keys[j] < key) ? 1 : 0;
            if (rank < 64) s_out[rank] = (int)(unsigned)(key & 0xFFFFFFFFu);
        }
    }
}

// ---------------- feature transpose: (B,C,N) fp32 -> (B,N,C) bf16, vectorized ----------------
__global__ __launch_bounds__(256) void transpose_kernel(const float* __restrict__ feat,
                                                        ushort* __restrict__ featT) {
    int t = blockIdx.x;
    int b = t >> 10;
    int rem = t & 1023;
    int cblk = rem >> 8;   // 0..3
    int nblk = rem & 255;  // 0..255
    __shared__ float tile[64][65];
    int tid = threadIdx.x;
    // load: 4x float4 per thread (16B/lane, coalesced 256B per 16-lane group)
    for (int i = tid; i < 1024; i += 256) {
        int cy = i >> 4, nx4 = (i & 15) * 4;
        float4 v = *(const float4*)&feat[((size_t)(b * C_ + cblk * 64 + cy)) * N_ +
                                         nblk * 64 + nx4];
        tile[cy][nx4 + 0] = v.x;
        tile[cy][nx4 + 1] = v.y;
        tile[cy][nx4 + 2] = v.z;
        tile[cy][nx4 + 3] = v.w;
    }
    __syncthreads();
    // store: 4x uint2 per thread = 4 bf16 channels each (512B per row-group, coalesced)
    for (int i = tid; i < 1024; i += 256) {
        int ny = i >> 4, c4 = i & 15;
        uint32_t lo = f2bf(tile[c4 * 4 + 0][ny]) | (f2bf(tile[c4 * 4 + 1][ny]) << 16);
        uint32_t hi = f2bf(tile[c4 * 4 + 2][ny]) | (f2bf(tile[c4 * 4 + 3][ny]) << 16);
        uint2 v;
        v.x = lo;
        v.y = hi;
        *(uint2*)&featT[((size_t)(b * N_ + nblk * 64 + ny)) * C_ + cblk * 64 + c4 * 4] = v;
    }
}

// ---------------- fused: cylinder query + group, one bp per block ----------------
__global__ __launch_bounds__(256) void qg_kernel(const ushort* __restrict__ featT,
                                                 const float* __restrict__ features,
                                                 const float* __restrict__ xyz,
                                                 const float* __restrict__ new_xyz,
                                                 const float* __restrict__ rot,
                                                 float* __restrict__ out, int useT) {
    __shared__ USmem sm;
    __shared__ int s_idx[S_];
    const int tid = threadIdx.x;
    const int lane = tid & 63;
    const int bp = blockIdx.x;
    const int b = bp >> 10;
    const int p = bp & 1023;

    if (tid == 0) sm.qs.cnt = 0;

    const float cx = new_xyz[bp * 3 + 0];
    const float cy = new_xyz[bp * 3 + 1];
    const float cz = new_xyz[bp * 3 + 2];
    const float* R = rot + (size_t)bp * 9;
    const float r0 = R[0], r1 = R[1], r2 = R[2];
    const float r3 = R[3], r4 = R[4], r5 = R[5];
    const float r6 = R[6], r7 = R[7], r8 = R[8];

    __syncthreads();  // cnt initialized

    const float* xb = xyz + (size_t)b * N_ * 3;
    const float4* xb4 = (const float4*)xb;

    // ---- query main pass: 4 points/thread/iter via 3x dwordx4 ----
    for (int it = 0; it < N_ / 1024; ++it) {
        int t4 = it * 256 + tid;
        float4 A = xb4[t4 * 3 + 0];
        float4 Bv = xb4[t4 * 3 + 1];
        float4 Cv = xb4[t4 * 3 + 2];
        int n0 = t4 * 4;

        uint32_t s0 = eval_sb(A.x, A.y, A.z, cx, cy, cz, r0, r1, r2, r3, r4, r5, r6, r7, r8);
        uint32_t s1 = eval_sb(A.w, Bv.x, Bv.y, cx, cy, cz, r0, r1, r2, r3, r4, r5, r6, r7, r8);
        uint32_t s2 = eval_sb(Bv.z, Bv.w, Cv.x, cx, cy, cz, r0, r1, r2, r3, r4, r5, r6, r7, r8);
        uint32_t s3 = eval_sb(Cv.y, Cv.z, Cv.w, cx, cy, cz, r0, r1, r2, r3, r4, r5, r6, r7, r8);

        if (it == 0 && tid < 32) {
            sm.qs.vflag[n0 + 0] = (s0 != INF_BITS) ? 1 : 0;
            sm.qs.vflag[n0 + 1] = (s1 != INF_BITS) ? 1 : 0;
            sm.qs.vflag[n0 + 2] = (s2 != INF_BITS) ? 1 : 0;
            sm.qs.vflag[n0 + 3] = (s3 != INF_BITS) ? 1 : 0;
        }
        uint32_t mn = min(min(s0, s1), min(s2, s3));
        if (__any(mn != INF_BITS)) {
            uint32_t sb[4] = {s0, s1, s2, s3};
#pragma unroll
            for (int j = 0; j < 4; ++j) {
                u64 m = __ballot(sb[j] != INF_BITS);
                if (m) {  // wave-uniform
                    int leader = __builtin_ctzll(m);
                    int cnt = __popcll(m);
                    int base = 0;
                    if (lane == leader) base = atomicAdd(&sm.qs.cnt, cnt);
                    base = __shfl(base, leader, 64);
                    if (sb[j] != INF_BITS) {
                        int pos = base + __popcll(m & ((1ull << lane) - 1ull));
                        if (pos < CAP_) sm.qs.keys[pos] = ((u64)sb[j] << 32) | (unsigned)(n0 + j);
                    }
                }
            }
        }
    }
    __syncthreads();

    // ---- selection -> s_idx (LDS) ----
    select_idx(sm.qs, xb, cx, cy, cz, r0, r1, r2, r3, r4, r5, r6, r7, r8, s_idx);
    __syncthreads();  // s_idx visible; qs no longer read (tile may overwrite union)

    // ---- group: xyz part (3 channels) ----
    if (tid < S_) {
        int n = s_idx[tid];
        const float* pt = xyz + ((size_t)b * N_ + n) * 3;
        float dx = pt[0] - cx;
        float dy = pt[1] - cy;
        float dz = pt[2] - cz;
        // g_e = ((dx*R[0,e] + dy*R[1,e]) + dz*R[2,e]), no FMA
        float g0 = __fadd_rn(__fadd_rn(__fmul_rn(dx, r0), __fmul_rn(dy, r3)), __fmul_rn(dz, r6));
        float g1 = __fadd_rn(__fadd_rn(__fmul_rn(dx, r1), __fmul_rn(dy, r4)), __fmul_rn(dz, r7));
        float g2 = __fadd_rn(__fadd_rn(__fmul_rn(dx, r2), __fmul_rn(dy, r5)), __fmul_rn(dz, r8));
        out[(((size_t)b * CH_ + 0) * P_ + p) * S_ + tid] = g0;
        out[(((size_t)b * CH_ + 1) * P_ + p) * S_ + tid] = g1;
        out[(((size_t)b * CH_ + 2) * P_ + p) * S_ + tid] = g2;
    }

    // ---- group: features, two s-halves of 32 samples each ----
    for (int h = 0; h < 2; ++h) {
        if (h) __syncthreads();  // protect tile reuse
        // Phase A: gather 32 bf16 rows into tileu[sl][cp] (sample-major)
        if (useT) {
            // uint4 per lane (8 channels); 512B per gathered row across 32 lanes
            for (int i = tid; i < 32 * 32; i += 256) {
                int sl = i >> 5, cq = i & 31;
                int n = s_idx[h * 32 + sl];
                uint4 v = *(const uint4*)&featT[((size_t)b * N_ + n) * C_ + cq * 8];
                *(uint4*)&sm.g.tileu[sl][cq * 4] = v;
            }
        } else {
            // fallback (no workspace): scalar gathers from (C,N), pack to bf16
            for (int i = tid; i < 32 * 128; i += 256) {
                int sl = i >> 7, cp = i & 127;
                int n = s_idx[h * 32 + sl];
                uint32_t u0 = f2bf(features[((size_t)b * C_ + 2 * cp + 0) * N_ + n]);
                uint32_t u1 = f2bf(features[((size_t)b * C_ + 2 * cp + 1) * N_ + n]);
                sm.g.tileu[sl][cp] = u0 | (u1 << 16);
            }
        }
        __syncthreads();
        // Phase B: each thread reads 4 uints (2-way LDS, free) and emits TWO float4
        // stores (c=2cp, 2cp+1); 8 q-lanes per c -> 128B contiguous lines.
        for (int i = tid; i < (C_ / 2) * 8; i += 256) {
            int cp = i >> 3, q = i & 7;
            uint32_t u0 = sm.g.tileu[4 * q + 0][cp];
            uint32_t u1 = sm.g.tileu[4 * q + 1][cp];
            uint32_t u2 = sm.g.tileu[4 * q + 2][cp];
            uint32_t u3 = sm.g.tileu[4 * q + 3][cp];
            float4 lo, hi;
            lo.x = bf2f(u0 & 0xffffu); lo.y = bf2f(u1 & 0xffffu);
            lo.z = bf2f(u2 & 0xffffu); lo.w = bf2f(u3 & 0xffffu);
            hi.x = bf2f(u0 >> 16); hi.y = bf2f(u1 >> 16);
            hi.z = bf2f(u2 >> 16); hi.w = bf2f(u3 >> 16);
            size_t base0 = (((size_t)b * CH_ + 3 + 2 * cp) * P_ + p) * S_ + h * 32 + 4 * q;
            *(float4*)&out[base0] = lo;
            *(float4*)&out[base0 + (size_t)P_ * S_] = hi;
        }
    }
}

extern "C" void kernel_launch(void* const* d_in, const int* in_sizes, int n_in,
                              void* d_out, int out_size, void* d_ws, size_t ws_size,
                              hipStream_t stream) {
    const float* xyz = (const float*)d_in[0];       // (B,N,3)
    const float* new_xyz = (const float*)d_in[1];   // (B,P,3)
    const float* rot = (const float*)d_in[2];       // (B,P,3,3)
    const float* features = (const float*)d_in[3];  // (B,C,N)
    float* out = (float*)d_out;

    const size_t featT_bytes = (size_t)B_ * N_ * C_ * sizeof(ushort);  // 16.8 MB
    const int useT = (ws_size >= featT_bytes) ? 1 : 0;

    ushort* featT = (ushort*)d_ws;

    if (useT) {
        transpose_kernel<<<2048, 256, 0, stream>>>(features, featT);
    }
    qg_kernel<<<B_ * P_, 256, 0, stream>>>(featT, features, xyz, new_xyz, rot, out, useT);
}